// Round 11
// baseline (2231.606 us; speedup 1.0000x reference)
//
#include <hip/hip_runtime.h>
#include <math.h>

#define HH 160
#define WW 180
#define HWSZ (HH*WW)
#define BB 8
#define BB2 16                           // both branches merged in z
#define P1 ((size_t)BB*HWSZ)             // 230400 (one branch, one plane)
#define PE2 ((size_t)BB2*32*HWSZ)        // merged 32-ch plane set (both branches)

typedef unsigned short u16;
typedef unsigned long long ull;
typedef __attribute__((ext_vector_type(8))) short short8;
typedef __attribute__((ext_vector_type(2))) unsigned long long ull2;
typedef __attribute__((ext_vector_type(4))) float floatx4;

struct Ptrs16 { const float* p[16]; };

// ---------------- bf16 helpers ----------------
__device__ __forceinline__ u16 f2b(float f) {
  unsigned u = __builtin_bit_cast(unsigned, f);
  unsigned r = (u + 0x7fffu + ((u >> 16) & 1u)) >> 16;
  return (u16)r;
}
__device__ __forceinline__ float b2f(u16 h) {
  return __builtin_bit_cast(float, ((unsigned)h) << 16);
}

// ---------------- activation (eq. 33), delta = 0.01 ----------------
__device__ __forceinline__ float actf(float x) {
  float q = x*x*25.0f + 0.5f*x + 0.0025f;
  float r = fmaxf(x, 0.0f);
  return (fabsf(x) > 0.01f) ? r : q;
}
__device__ __forceinline__ float actdf(float x) {
  float q = x*50.0f + 0.5f;
  float r = (x > 0.0f) ? 1.0f : 0.0f;
  return (fabsf(x) > 0.01f) ? r : q;
}

// ---------------- weight prep, all 12 slots in one dispatch ----------------
// fp32 [o][c][9] -> bf16 [tap][nt][plane(r,i,-i)][o16][c32], 27648 u16 per slot
__global__ void prep_all(Ptrs16 ps, u16* __restrict__ dst0) {
  const int rIdx[12] = {2,4,6,6,4,2,10,12,14,14,12,10};
  const int bwdF[12] = {0,0,0,1,1,1,0,0,0,1,1,1};
  int slot = blockIdx.x / 36;
  int idx = (blockIdx.x % 36)*256 + threadIdx.x;
  if (idx >= 9*32*32) return;
  const float* wr = ps.p[rIdx[slot]];
  const float* wi = ps.p[rIdx[slot]+1];
  u16* dst = dst0 + (size_t)slot*27648;
  int tap = idx >> 10; int rem = idx & 1023; int o = rem >> 5; int c = rem & 31;
  int s = bwdF[slot] ? ((c*32 + o)*9 + (8 - tap)) : ((o*32 + c)*9 + tap);
  float vr = wr[s], vi = wi[s];
  int nt = o >> 4, m = o & 15;
  size_t base = ((((size_t)tap*2 + nt)*3)*16 + (size_t)m)*32 + c;
  dst[base]        = f2b(vr);
  dst[base + 512]  = f2b(vi);
  dst[base + 1024] = f2b(-vi);
}

// ---------------- MFMA complex conv 32->32, 3x3 SAME, implicit GEMM -----------------
// NHWC bf16: addr = ((b*HH+y)*WW+x)*32 + ch, R at 0, I at +PE2. b in [0,16): branch=b>>3.
// Tile 32x4, 4 waves (wave=row), 2 m-segments, 256 threads. LDS 29.4 KB -> 5 blocks/CU
// (the R10 48-wide/hoisted variant was MLP-bound at 3 blocks/CU; stride back to 36 =
// 72B = 16-bank cycle, R7-proven). In-loop weight loads (L1-resident, R7-proven).
// OPERAND-SWAPPED MFMA: A=weights (M=och), B=pixels (N=px) -> D row=och, col=px.
// MODE: 0 plain, 1 act, 2 cmul by actdf(der), 3 channel-norm normalize (fused)
template<int MODE>
__global__ __launch_bounds__(256)
void conv_mfma(const u16* __restrict__ inb, const u16* __restrict__ wbA,
               const u16* __restrict__ wbB, u16* __restrict__ outb,
               const u16* __restrict__ derb,
               const float* __restrict__ thrA, const float* __restrict__ thrB)
{
  __shared__ alignas(16) u16 stg[2*6*34*36];   // 29376 B
  const int tid = threadIdx.x;
  const int lane = tid & 63, wv = tid >> 6;
  const int x0 = blockIdx.x * 32, y0 = blockIdx.y * 4, b = blockIdx.z;
  const u16* wb = (b < BB) ? wbA : wbB;
  constexpr int PL = 6*34*36;
  const int m = lane & 15, q = lane >> 4;

  // ---- stage: 1632 16B chunks (plane,row6,col34,chq4), coalesced NHWC reads ----
  for (int j = tid; j < 1632; j += 256) {
    int prow = j / 136; int rem = j - prow*136;
    int col = rem >> 2, chq = rem & 3;
    int plane = prow / 6, row = prow - plane*6;
    int gy = y0 - 1 + row, gx = x0 - 1 + col;
    ull v0 = 0, v1 = 0;
    if (gy >= 0 && gy < HH && gx >= 0 && gx < WW) {
      const ull* src = (const ull*)(inb + (size_t)plane*PE2
                                    + (((size_t)b*HH + gy)*WW + gx)*32 + chq*8);
      v0 = src[0]; v1 = src[1];
    }
    ull* dst = (ull*)&stg[((size_t)prow*34 + col)*36 + chq*8];
    dst[0] = v0; dst[1] = v1;
  }
  __syncthreads();

  floatx4 accr[2][2], acci[2][2];   // [seg][nt]
#pragma unroll
  for (int s = 0; s < 2; ++s)
#pragma unroll
    for (int nt = 0; nt < 2; ++nt) {
      accr[s][nt] = (floatx4){0.f,0.f,0.f,0.f};
      acci[s][nt] = (floatx4){0.f,0.f,0.f,0.f};
    }

#pragma unroll
  for (int tap = 0; tap < 9; ++tap) {
    const int ky = tap / 3, kx = tap - ky*3;
    short8 Pr[2], Pi[2];     // pixel fragments: B[k=ch][n=px], 8B-aligned dual-ull
#pragma unroll
    for (int s = 0; s < 2; ++s) {
      int cu = ((wv + ky)*34 + (s*16 + m + kx))*36 + q*8;
      const ull* pR = (const ull*)&stg[cu];
      const ull* pI = (const ull*)&stg[cu + PL];
      ull2 vr; vr.x = pR[0]; vr.y = pR[1];
      ull2 vi; vi.x = pI[0]; vi.y = pI[1];
      Pr[s] = __builtin_bit_cast(short8, vr);
      Pi[s] = __builtin_bit_cast(short8, vi);
    }
#pragma unroll
    for (int nt = 0; nt < 2; ++nt) {
      const u16* pw = wb + ((size_t)(tap*2 + nt)*3)*512 + (size_t)m*32 + q*8;
      short8 Wr  = *(const short8*)pw;          // weight frags: A[m=och][k=ch]
      short8 Wi  = *(const short8*)(pw + 512);
      short8 nWi = *(const short8*)(pw + 1024);
#pragma unroll
      for (int s = 0; s < 2; ++s) {
        accr[s][nt] = __builtin_amdgcn_mfma_f32_16x16x32_bf16(Wr,  Pr[s], accr[s][nt], 0, 0, 0);
        accr[s][nt] = __builtin_amdgcn_mfma_f32_16x16x32_bf16(nWi, Pi[s], accr[s][nt], 0, 0, 0);
        acci[s][nt] = __builtin_amdgcn_mfma_f32_16x16x32_bf16(Wr,  Pi[s], acci[s][nt], 0, 0, 0);
        acci[s][nt] = __builtin_amdgcn_mfma_f32_16x16x32_bf16(Wi,  Pr[s], acci[s][nt], 0, 0, 0);
      }
    }
  }

  // ---- direct epilogue: lane holds px = x0+s*16+m, och = nt*16+q*4+r in regs ----
  const int y = y0 + wv;
#pragma unroll
  for (int s = 0; s < 2; ++s) {
    int x = x0 + s*16 + m;
    bool ok = (x < WW);
    float invn = 1.0f;
    if constexpr (MODE == 3) {
      float ss = 0.f;
#pragma unroll
      for (int nt = 0; nt < 2; ++nt)
#pragma unroll
        for (int r = 0; r < 4; ++r)
          ss += accr[s][nt][r]*accr[s][nt][r] + acci[s][nt][r]*acci[s][nt][r];
      ss += __shfl_xor(ss, 16, 64);    // sum over q (lane bits 4,5): full 32-och norm
      ss += __shfl_xor(ss, 32, 64);
      float thr = (b < BB ? thrA : thrB)[0];
      invn = 1.0f / fmaxf(sqrtf(ss), thr);
    }
    size_t pxbase = (((size_t)b*HH + y)*WW + x)*32;
#pragma unroll
    for (int nt = 0; nt < 2; ++nt) {
      size_t gb = pxbase + nt*16 + q*4;
      ull dR = 0, dI = 0;
      if constexpr (MODE == 2) {
        if (ok) { dR = *(const ull*)(derb + gb); dI = *(const ull*)(derb + PE2 + gb); }
      }
      ull vR = 0, vI = 0;
#pragma unroll
      for (int r = 0; r < 4; ++r) {
        float pr = accr[s][nt][r], pi = acci[s][nt][r];
        if constexpr (MODE == 1) { pr = actf(pr); pi = actf(pi); }
        if constexpr (MODE == 3) { pr *= invn; pi *= invn; }
        if constexpr (MODE == 2) {
          float dr = actdf(b2f((u16)(dR >> (16*r))));
          float di = actdf(b2f((u16)(dI >> (16*r))));
          float nr = pr*dr - pi*di;
          pi = pr*di + pi*dr; pr = nr;
        }
        vR |= (ull)f2b(pr) << (16*r);
        vI |= (ull)f2b(pi) << (16*r);
      }
      if (ok) {
        *(ull*)(outb + gb)       = vR;
        *(ull*)(outb + PE2 + gb) = vI;
      }
    }
  }
}

// ---------------- layer-1 forward: complex conv 1->32 + act, planar fp32 -> NHWC bf16
// 8x8 px tile; 256 threads: og = tid&3 (8 och each), px = tid>>2 (lx=px&7, ly=px>>3).
__global__ __launch_bounds__(256)
void l1fwd(const float* __restrict__ xall,
           const float* __restrict__ wrA, const float* __restrict__ wiA,
           const float* __restrict__ wrB, const float* __restrict__ wiB,
           u16* __restrict__ outb)
{
  __shared__ float hR[10][12], hI[10][12];
  __shared__ float wt[9][32][2];
  const int tid = threadIdx.x;
  const int og = tid & 3, px = tid >> 2;
  const int lx = px & 7, ly = px >> 3;
  const int x0 = blockIdx.x*8, y0 = blockIdx.y*8, b = blockIdx.z;
  const int branch = b >> 3, img = b & 7;
  const float* wr = branch ? wrB : wrA;
  const float* wi = branch ? wiB : wiA;
  const float* xp = xall + (size_t)branch*2*P1 + (size_t)img*HWSZ;

  for (int j = tid; j < 576; j += 256) {
    int tap = j >> 6; int rem = j & 63; int o = rem >> 1, ri = rem & 1;
    wt[tap][o][ri] = ri ? wi[o*9+tap] : wr[o*9+tap];
  }
  for (int j = tid; j < 200; j += 256) {
    int plane = j / 100; int pos = j - plane*100;
    int yy = pos / 10, xx = pos - yy*10;
    int gy = y0 - 1 + yy, gx = x0 - 1 + xx;
    float v = 0.f;
    if (gy >= 0 && gy < HH && gx >= 0 && gx < WW)
      v = xp[(size_t)plane*P1 + (size_t)gy*WW + gx];
    (plane ? hI : hR)[yy][xx] = v;
  }
  __syncthreads();

  float accR[8], accI[8];
#pragma unroll
  for (int o = 0; o < 8; ++o) { accR[o] = 0.f; accI[o] = 0.f; }
#pragma unroll
  for (int tap = 0; tap < 9; ++tap) {
    int ky = tap/3, kx = tap - ky*3;
    float ar = hR[ly+ky][lx+kx], ai = hI[ly+ky][lx+kx];
#pragma unroll
    for (int o = 0; o < 8; ++o) {
      float wrv = wt[tap][og*8+o][0], wiv = wt[tap][og*8+o][1];
      accR[o] += ar*wrv - ai*wiv;
      accI[o] += ar*wiv + ai*wrv;
    }
  }
  int gx = x0 + lx, gy = y0 + ly;
  if (gx < WW) {
    size_t base = (((size_t)b*HH + gy)*WW + gx)*32 + og*8;
    ull* dR = (ull*)(outb + base);
    ull* dI = (ull*)(outb + PE2 + base);
#pragma unroll
    for (int k = 0; k < 2; ++k) {
      ull vR = 0, vI = 0;
#pragma unroll
      for (int t = 0; t < 4; ++t) {
        vR |= (ull)f2b(actf(accR[k*4+t])) << (16*t);
        vI |= (ull)f2b(actf(accI[k*4+t])) << (16*t);
      }
      dR[k] = vR; dI[k] = vI;
    }
  }
}

// ---------------- layer-1 backward: complex convT 32->1, NHWC bf16 -> planar fp32 ----
// 8x8 px tile; 256 threads: cg = tid&3 (8 ch each), px = tid>>2; quad shfl reduce.
__global__ __launch_bounds__(256)
void l1bwd(const u16* __restrict__ gb,
           const float* __restrict__ wrA, const float* __restrict__ wiA,
           const float* __restrict__ wrB, const float* __restrict__ wiB,
           float* __restrict__ outp)
{
  __shared__ alignas(16) u16 stg[2*100*32];   // [plane][pos10x10][ch32] = 12.5 KB
  __shared__ float wt[32][9][2];
  const int tid = threadIdx.x;
  const int cg = tid & 3, px = tid >> 2;
  const int lx = px & 7, ly = px >> 3;
  const int x0 = blockIdx.x*8, y0 = blockIdx.y*8, b = blockIdx.z;
  const int branch = b >> 3, img = b & 7;
  const float* wr = branch ? wrB : wrA;
  const float* wi = branch ? wiB : wiA;

  for (int j = tid; j < 576; j += 256) {
    int c = j / 18; int rem = j - c*18; int tap = rem >> 1, ri = rem & 1;
    wt[c][tap][ri] = (ri ? wi : wr)[c*9 + (8-tap)];
  }
  // stage halo: 800 16B chunks (2 planes x 100 pos x 4 chq)
  for (int j = tid; j < 800; j += 256) {
    int plane = j / 400; int rem = j - plane*400;
    int pos = rem >> 2, chq = rem & 3;
    int yy = pos / 10, xx = pos - yy*10;
    int gy = y0 - 1 + yy, gx = x0 - 1 + xx;
    ull v0 = 0, v1 = 0;
    if (gy >= 0 && gy < HH && gx >= 0 && gx < WW) {
      const ull* src = (const ull*)(gb + (size_t)plane*PE2
                                    + (((size_t)b*HH + gy)*WW + gx)*32 + chq*8);
      v0 = src[0]; v1 = src[1];
    }
    ull* dst = (ull*)&stg[((size_t)plane*100 + pos)*32 + chq*8];
    dst[0] = v0; dst[1] = v1;
  }
  __syncthreads();

  float gr = 0.f, gi = 0.f;
#pragma unroll
  for (int tap = 0; tap < 9; ++tap) {
    int ky = tap/3, kx = tap - ky*3;
    int pos = (ly+ky)*10 + (lx+kx);
    const ull* pR = (const ull*)&stg[(size_t)pos*32 + cg*8];
    const ull* pI = (const ull*)&stg[(100 + (size_t)pos)*32 + cg*8];
    ull r0 = pR[0], r1 = pR[1], i0 = pI[0], i1 = pI[1];
#pragma unroll
    for (int t = 0; t < 4; ++t) {
      int c = cg*8 + t;
      float ar = b2f((u16)(r0 >> (16*t))), ai = b2f((u16)(i0 >> (16*t)));
      float wrv = wt[c][tap][0], wiv = wt[c][tap][1];
      gr += ar*wrv - ai*wiv;
      gi += ar*wiv + ai*wrv;
    }
#pragma unroll
    for (int t = 0; t < 4; ++t) {
      int c = cg*8 + 4 + t;
      float ar = b2f((u16)(r1 >> (16*t))), ai = b2f((u16)(i1 >> (16*t)));
      float wrv = wt[c][tap][0], wiv = wt[c][tap][1];
      gr += ar*wrv - ai*wiv;
      gi += ar*wiv + ai*wrv;
    }
  }
  gr += __shfl_xor(gr, 1, 64); gr += __shfl_xor(gr, 2, 64);
  gi += __shfl_xor(gi, 1, 64); gi += __shfl_xor(gi, 2, 64);

  int gx = x0 + lx, gy = y0 + ly;
  if (cg == 0 && gx < WW) {
    size_t o2 = (size_t)branch*2*P1 + (size_t)img*HWSZ + (size_t)gy*WW + gx;
    outp[o2]      = gr;
    outp[P1 + o2] = gi;
  }
}

// ---------------- DFT machinery ----------------
__global__ void gen_dft2(float2* __restrict__ Mf, float2* __restrict__ Mi, int N) {
  int idx = blockIdx.x*256 + threadIdx.x;
  if (idx >= N*N) return;
  int r = idx / N, c = idx - r*N;
  long mm = ((long)r * (long)c) % N;
  double a = 2.0 * 3.14159265358979323846 * (double)mm / (double)N;
  double cs = cos(a), sn = sin(a);
  Mf[idx] = make_float2((float)cs, (float)(-sn));
  Mi[idx] = make_float2((float)(cs/N), (float)(sn/N));
}

// row-DFT from planar x (both branches): bh over [0, 16*HH)
__global__ void dft_row_planes(const float* __restrict__ xall,
                               float2* __restrict__ out, const float2* __restrict__ M) {
  int bh = blockIdx.x;
  int v = threadIdx.x; if (v >= WW) return;
  int b2 = bh / HH, h = bh - b2*HH;
  int branch = b2 >> 3, img = b2 & 7;
  const float* rowR = xall + (size_t)branch*2*P1 + (size_t)img*HWSZ + (size_t)h*WW;
  const float* rowI = rowR + P1;
  float ar = 0.f, ai = 0.f;
  for (int w = 0; w < WW; ++w) {
    float sr = rowR[w], si = rowI[w];
    float2 m = M[w*WW + v];
    ar += sr*m.x - si*m.y;
    ai += sr*m.y + si*m.x;
  }
  out[(size_t)bh*WW + v] = make_float2(ar, ai);
}

__global__ void dft_row_c(const float2* __restrict__ in, float2* __restrict__ out,
                          const float2* __restrict__ M) {
  int bh = blockIdx.x;
  int v = threadIdx.x; if (v >= WW) return;
  const float2* row = in + (size_t)bh*WW;
  float ar = 0.f, ai = 0.f;
  for (int w = 0; w < WW; ++w) {
    float2 s = row[w];
    float2 m = M[w*WW + v];
    ar += s.x*m.x - s.y*m.y;
    ai += s.x*m.y + s.y*m.x;
  }
  out[(size_t)bh*WW + v] = make_float2(ar, ai);
}

__global__ void dft_col_c(const float2* __restrict__ in, float2* __restrict__ out,
                          const float2* __restrict__ M) {
  int bu = blockIdx.x;
  int v = threadIdx.x; if (v >= WW) return;
  int b = bu / HH, u = bu - b*HH;
  const float2* base = in + (size_t)b*HWSZ;
  float ar = 0.f, ai = 0.f;
  for (int h = 0; h < HH; ++h) {
    float2 m = M[u*HH + h];
    float2 s = base[(size_t)h*WW + v];
    ar += s.x*m.x - s.y*m.y;
    ai += s.x*m.y + s.y*m.x;
  }
  out[(size_t)bu*WW + v] = make_float2(ar, ai);
}

// col-iDFT with fused mask^2 on input element (h,v)
__global__ void dft_col_mask(const float2* __restrict__ in, float2* __restrict__ out,
                             const float2* __restrict__ M, const float* __restrict__ mask) {
  int bu = blockIdx.x;
  int v = threadIdx.x; if (v >= WW) return;
  int b = bu / HH, u = bu - b*HH;
  const float2* base = in + (size_t)b*HWSZ;
  float ar = 0.f, ai = 0.f;
  for (int h = 0; h < HH; ++h) {
    float mk = mask[h*WW + v]; float mm = mk*mk;
    float2 m = M[u*HH + h];
    float2 s = base[(size_t)h*WW + v];
    float sr = s.x*mm, si = s.y*mm;
    ar += sr*m.x - si*m.y;
    ai += sr*m.y + si*m.x;
  }
  out[(size_t)bu*WW + v] = make_float2(ar, ai);
}

// final row-iDFT fused with x update: x -= a*(gradf - ct) + bet*gr
__global__ void dft_row_update(const float2* __restrict__ in, const float2* __restrict__ M,
                               const float2* __restrict__ ctall, const float* __restrict__ grp,
                               float* __restrict__ xall,
                               const float* __restrict__ al1, const float* __restrict__ al2,
                               const float* __restrict__ be1, const float* __restrict__ be2,
                               int phase) {
  int bh = blockIdx.x;
  int v = threadIdx.x; if (v >= WW) return;
  int b2 = bh / HH, h = bh - b2*HH;
  int branch = b2 >> 3, img = b2 & 7;
  const float2* row = in + (size_t)bh*WW;
  float ar = 0.f, ai = 0.f;
  for (int w = 0; w < WW; ++w) {
    float2 s = row[w];
    float2 m = M[w*WW + v];
    ar += s.x*m.x - s.y*m.y;
    ai += s.x*m.y + s.y*m.x;
  }
  float2 ct = ctall[(size_t)bh*WW + v];
  float a   = (branch ? al2 : al1)[phase];
  float bet = (branch ? be2 : be1)[phase];
  size_t xo = (size_t)branch*2*P1 + (size_t)img*HWSZ + (size_t)h*WW + v;
  xall[xo]      -= a*(ar - ct.x) + bet*grp[xo];
  xall[P1 + xo] -= a*(ai - ct.y) + bet*grp[P1 + xo];
}

// ---------------- small pointwise kernels ----------------
__global__ void maskk_m(const float* __restrict__ k1, const float* __restrict__ k2,
                        const float* __restrict__ mask, float2* __restrict__ t) {
  int i = blockIdx.x*256 + threadIdx.x;
  if (i >= (int)(2*P1)) return;
  int branch = i >= (int)P1;
  int ii = i - branch*(int)P1;
  int b = ii / HWSZ, p = ii - b*HWSZ;
  const float* k = branch ? k2 : k1;
  float m = mask[p];
  t[i] = make_float2(m * k[(size_t)b*2*HWSZ + p], m * k[(size_t)b*2*HWSZ + HWSZ + p]);
}

__global__ void unpack_m(const float* __restrict__ x1, const float* __restrict__ x2,
                         float* __restrict__ xall) {
  int i = blockIdx.x*256 + threadIdx.x;
  if (i >= (int)(2*P1)) return;
  int branch = i >= (int)P1;
  int ii = i - branch*(int)P1;
  int b = ii / HWSZ, p = ii - b*HWSZ;
  const float* src = branch ? x2 : x1;
  size_t dst = (size_t)branch*2*P1 + (size_t)b*HWSZ + p;
  xall[dst]      = src[(size_t)b*2*HWSZ + p];
  xall[P1 + dst] = src[(size_t)b*2*HWSZ + HWSZ + p];
}

__global__ void pack_kernel(const float* __restrict__ xall, float* __restrict__ out) {
  int i = blockIdx.x*256 + threadIdx.x;
  if (i >= (int)P1) return;
  int b = i / HWSZ, p = i - b*HWSZ;
  size_t ob = (size_t)b*4*HWSZ;
  size_t x1o = (size_t)b*HWSZ + p;
  size_t x2o = 2*P1 + x1o;
  out[ob + p]          = xall[x1o];
  out[ob + HWSZ + p]   = xall[P1 + x1o];
  out[ob + 2*HWSZ + p] = xall[x2o];
  out[ob + 3*HWSZ + p] = xall[P1 + x2o];
}

// ---------------- launch ----------------
extern "C" void kernel_launch(void* const* d_in, const int* in_sizes, int n_in,
                              void* d_out, int out_size, void* d_ws, size_t ws_size,
                              hipStream_t stream) {
  (void)in_sizes; (void)n_in; (void)out_size; (void)ws_size;
  const float* x1in = (const float*)d_in[0];
  const float* x2in = (const float*)d_in[1];
  const float* k1   = (const float*)d_in[2];
  const float* k2   = (const float*)d_in[3];
  const float* mask = (const float*)d_in[4];
  Ptrs16 cw;
  for (int i = 0; i < 16; ++i) cw.p[i] = (const float*)d_in[5+i];
  const float* thr1 = (const float*)d_in[21];
  const float* thr2 = (const float*)d_in[22];
  const float* al1  = (const float*)d_in[23];
  const float* al2  = (const float*)d_in[24];
  const float* be1  = (const float*)d_in[25];
  const float* be2  = (const float*)d_in[26];
  float* out = (float*)d_out;

  // ---- workspace: bf16 region then fp32 region ----
  u16* U = (u16*)d_ws;
  size_t uoff = 0;
  auto alloc_u = [&](size_t n){ u16* p = U + uoff; uoff += (n + 15) & ~(size_t)15; return p; };
  u16* act1 = alloc_u(2*PE2);
  u16* act2 = alloc_u(2*PE2);
  u16* act3 = alloc_u(2*PE2);
  u16* w4b  = alloc_u(2*PE2);
  u16* wp0  = alloc_u(12*27648);

  float* F = (float*)(U + uoff);
  size_t off = 0;
  auto alloc_f = [&](size_t n){ float* p = F + off; off += (n + 3) & ~(size_t)3; return p; };
  float*  xall = alloc_f(4*P1);                       // [branch][plane][P1]
  float*  grp  = alloc_f(4*P1);
  float2* t1   = (float2*)alloc_f(4*P1);              // [16][HWSZ] complex
  float2* t2   = (float2*)alloc_f(4*P1);
  float2* ctall= (float2*)alloc_f(4*P1);
  float2* EWf  = (float2*)alloc_f(2*(size_t)WW*WW);
  float2* EWi  = (float2*)alloc_f(2*(size_t)WW*WW);
  float2* EHf  = (float2*)alloc_f(2*(size_t)HH*HH);
  float2* EHi  = (float2*)alloc_f(2*(size_t)HH*HH);

  const dim3 MG(6, 40, BB2);      // conv: 32x4 tiles, both branches (3840 blocks)
  const dim3 LG(23, 20, BB2);     // l1 convs: 8x8 tiles
  const int NP1 = (int)((P1 + 255)/256);
  const int NP2 = (int)((2*P1 + 255)/256);
  const int DFTG = BB2*HH;        // 2560
  const int DFTB = 192;

  gen_dft2<<<(WW*WW+255)/256, 256, 0, stream>>>(EWf, EWi, WW);
  gen_dft2<<<(HH*HH+255)/256, 256, 0, stream>>>(EHf, EHi, HH);
  prep_all<<<12*36, 256, 0, stream>>>(cw, wp0);
  unpack_m<<<NP2, 256, 0, stream>>>(x1in, x2in, xall);

  // cterm = ifft2(mask*k), both branches
  maskk_m<<<NP2, 256, 0, stream>>>(k1, k2, mask, t1);
  dft_col_c<<<DFTG, DFTB, 0, stream>>>(t1, t2, EHi);
  dft_row_c<<<DFTG, DFTB, 0, stream>>>(t2, ctall, EWi);

  u16* WA[6]; u16* WB[6];
  for (int i = 0; i < 6; ++i) { WA[i] = wp0 + (size_t)i*27648; WB[i] = wp0 + (size_t)(6+i)*27648; }

  for (int ph = 0; ph < 3; ++ph) {
    // grad_r both branches
    l1fwd<<<LG, 256, 0, stream>>>(xall, cw.p[0], cw.p[1], cw.p[8], cw.p[9], act1);
    conv_mfma<1><<<MG, 256, 0, stream>>>(act1, WA[0], WB[0], act2, nullptr, nullptr, nullptr);
    conv_mfma<1><<<MG, 256, 0, stream>>>(act2, WA[1], WB[1], act3, nullptr, nullptr, nullptr);
    conv_mfma<3><<<MG, 256, 0, stream>>>(act3, WA[2], WB[2], w4b, nullptr, thr1, thr2);
    conv_mfma<2><<<MG, 256, 0, stream>>>(w4b,  WA[3], WB[3], act3, act3, nullptr, nullptr);
    conv_mfma<2><<<MG, 256, 0, stream>>>(act3, WA[4], WB[4], act2, act2, nullptr, nullptr);
    conv_mfma<2><<<MG, 256, 0, stream>>>(act2, WA[5], WB[5], act1, act1, nullptr, nullptr);
    l1bwd<<<LG, 256, 0, stream>>>(act1, cw.p[0], cw.p[1], cw.p[8], cw.p[9], grp);
    // grad_f both branches + fused update
    dft_row_planes<<<DFTG, DFTB, 0, stream>>>(xall, t1, EWf);
    dft_col_c<<<DFTG, DFTB, 0, stream>>>(t1, t2, EHf);
    dft_col_mask<<<DFTG, DFTB, 0, stream>>>(t2, t1, EHi, mask);
    dft_row_update<<<DFTG, DFTB, 0, stream>>>(t1, EWi, ctall, grp, xall,
                                              al1, al2, be1, be2, ph);
  }

  pack_kernel<<<NP1, 256, 0, stream>>>(xall, out);
}

// Round 12
// 2005.165 us; speedup vs baseline: 1.1129x; 1.1129x over previous
//
#include <hip/hip_runtime.h>
#include <math.h>

#define HH 160
#define WW 180
#define HWSZ (HH*WW)
#define BB 8
#define BB2 16                           // both branches merged in z
#define P1 ((size_t)BB*HWSZ)             // 230400 (one branch, one plane)
#define PE2 ((size_t)BB2*32*HWSZ)        // merged 32-ch plane set (both branches)

typedef unsigned short u16;
typedef unsigned long long ull;
typedef __attribute__((ext_vector_type(8))) short short8;
typedef __attribute__((ext_vector_type(2))) unsigned long long ull2;
typedef __attribute__((ext_vector_type(4))) float floatx4;

struct Ptrs16 { const float* p[16]; };

// ---------------- bf16 helpers ----------------
__device__ __forceinline__ u16 f2b(float f) {
  unsigned u = __builtin_bit_cast(unsigned, f);
  unsigned r = (u + 0x7fffu + ((u >> 16) & 1u)) >> 16;
  return (u16)r;
}
__device__ __forceinline__ float b2f(u16 h) {
  return __builtin_bit_cast(float, ((unsigned)h) << 16);
}

// ---------------- activation (eq. 33), delta = 0.01 ----------------
__device__ __forceinline__ float actf(float x) {
  float q = x*x*25.0f + 0.5f*x + 0.0025f;
  float r = fmaxf(x, 0.0f);
  return (fabsf(x) > 0.01f) ? r : q;
}
__device__ __forceinline__ float actdf(float x) {
  float q = x*50.0f + 0.5f;
  float r = (x > 0.0f) ? 1.0f : 0.0f;
  return (fabsf(x) > 0.01f) ? r : q;
}

// ---------------- weight prep, all 12 slots in one dispatch ----------------
// fp32 [o][c][9] -> bf16 [tap][nt][plane(r,i)][o16][c32], 18432 u16 per slot.
// Only 2 planes (36 KB) -> whole slot fits the 32 KB L1 almost exactly; -Wi is
// derived in-kernel by sign-bit XOR (R10-verified numerically exact).
__global__ void prep_all(Ptrs16 ps, u16* __restrict__ dst0) {
  const int rIdx[12] = {2,4,6,6,4,2,10,12,14,14,12,10};
  const int bwdF[12] = {0,0,0,1,1,1,0,0,0,1,1,1};
  int slot = blockIdx.x / 36;
  int idx = (blockIdx.x % 36)*256 + threadIdx.x;
  if (idx >= 9*32*32) return;
  const float* wr = ps.p[rIdx[slot]];
  const float* wi = ps.p[rIdx[slot]+1];
  u16* dst = dst0 + (size_t)slot*18432;
  int tap = idx >> 10; int rem = idx & 1023; int o = rem >> 5; int c = rem & 31;
  int s = bwdF[slot] ? ((c*32 + o)*9 + (8 - tap)) : ((o*32 + c)*9 + tap);
  float vr = wr[s], vi = wi[s];
  int nt = o >> 4, m = o & 15;
  size_t base = (((size_t)tap*2 + nt)*2*16 + (size_t)m)*32 + c;
  dst[base]       = f2b(vr);
  dst[base + 512] = f2b(vi);
}

// ---------------- MFMA complex conv 32->32, 3x3 SAME, implicit GEMM -----------------
// NHWC bf16: addr = ((b*HH+y)*WW+x)*32 + ch, R at 0, I at +PE2. b in [0,16): branch=b>>3.
// Tile 32x4, 4 waves (wave=row), 2 m-segments, 256 threads. LDS 29.4 KB -> 5 blocks/CU.
// Weights: Wr/Wi in-loop loads (36 KB slot = L1-resident), nWi by register XOR.
// OPERAND-SWAPPED MFMA: A=weights (M=och), B=pixels (N=px) -> D row=och, col=px.
// MODE: 0 plain, 1 act, 2 cmul by actdf(der), 3 channel-norm normalize (fused)
template<int MODE>
__global__ __launch_bounds__(256)
void conv_mfma(const u16* __restrict__ inb, const u16* __restrict__ wbA,
               const u16* __restrict__ wbB, u16* __restrict__ outb,
               const u16* __restrict__ derb,
               const float* __restrict__ thrA, const float* __restrict__ thrB)
{
  __shared__ alignas(16) u16 stg[2*6*34*36];   // 29376 B
  const int tid = threadIdx.x;
  const int lane = tid & 63, wv = tid >> 6;
  const int x0 = blockIdx.x * 32, y0 = blockIdx.y * 4, b = blockIdx.z;
  const u16* wb = (b < BB) ? wbA : wbB;
  constexpr int PL = 6*34*36;
  const int m = lane & 15, q = lane >> 4;

  // ---- stage: 1632 16B chunks (plane,row6,col34,chq4), coalesced NHWC reads ----
  for (int j = tid; j < 1632; j += 256) {
    int prow = j / 136; int rem = j - prow*136;
    int col = rem >> 2, chq = rem & 3;
    int plane = prow / 6, row = prow - plane*6;
    int gy = y0 - 1 + row, gx = x0 - 1 + col;
    ull v0 = 0, v1 = 0;
    if (gy >= 0 && gy < HH && gx >= 0 && gx < WW) {
      const ull* src = (const ull*)(inb + (size_t)plane*PE2
                                    + (((size_t)b*HH + gy)*WW + gx)*32 + chq*8);
      v0 = src[0]; v1 = src[1];
    }
    ull* dst = (ull*)&stg[((size_t)prow*34 + col)*36 + chq*8];
    dst[0] = v0; dst[1] = v1;
  }
  __syncthreads();

  floatx4 accr[2][2], acci[2][2];   // [seg][nt]
#pragma unroll
  for (int s = 0; s < 2; ++s)
#pragma unroll
    for (int nt = 0; nt < 2; ++nt) {
      accr[s][nt] = (floatx4){0.f,0.f,0.f,0.f};
      acci[s][nt] = (floatx4){0.f,0.f,0.f,0.f};
    }

#pragma unroll
  for (int tap = 0; tap < 9; ++tap) {
    const int ky = tap / 3, kx = tap - ky*3;
    short8 Pr[2], Pi[2];     // pixel fragments: B[k=ch][n=px], 8B-aligned dual-ull
#pragma unroll
    for (int s = 0; s < 2; ++s) {
      int cu = ((wv + ky)*34 + (s*16 + m + kx))*36 + q*8;
      const ull* pR = (const ull*)&stg[cu];
      const ull* pI = (const ull*)&stg[cu + PL];
      ull2 vr; vr.x = pR[0]; vr.y = pR[1];
      ull2 vi; vi.x = pI[0]; vi.y = pI[1];
      Pr[s] = __builtin_bit_cast(short8, vr);
      Pi[s] = __builtin_bit_cast(short8, vi);
    }
#pragma unroll
    for (int nt = 0; nt < 2; ++nt) {
      const u16* pw = wb + (size_t)(tap*2 + nt)*1024 + (size_t)m*32 + q*8;
      short8 Wr = *(const short8*)pw;           // weight frags: A[m=och][k=ch]
      short8 Wi = *(const short8*)(pw + 512);
      ull2 wx = __builtin_bit_cast(ull2, Wi);
      wx.x ^= 0x8000800080008000ULL;
      wx.y ^= 0x8000800080008000ULL;
      short8 nWi = __builtin_bit_cast(short8, wx);
#pragma unroll
      for (int s = 0; s < 2; ++s) {
        accr[s][nt] = __builtin_amdgcn_mfma_f32_16x16x32_bf16(Wr,  Pr[s], accr[s][nt], 0, 0, 0);
        accr[s][nt] = __builtin_amdgcn_mfma_f32_16x16x32_bf16(nWi, Pi[s], accr[s][nt], 0, 0, 0);
        acci[s][nt] = __builtin_amdgcn_mfma_f32_16x16x32_bf16(Wr,  Pi[s], acci[s][nt], 0, 0, 0);
        acci[s][nt] = __builtin_amdgcn_mfma_f32_16x16x32_bf16(Wi,  Pr[s], acci[s][nt], 0, 0, 0);
      }
    }
  }

  // ---- direct epilogue: lane holds px = x0+s*16+m, och = nt*16+q*4+r in regs ----
  const int y = y0 + wv;
#pragma unroll
  for (int s = 0; s < 2; ++s) {
    int x = x0 + s*16 + m;
    bool ok = (x < WW);
    float invn = 1.0f;
    if constexpr (MODE == 3) {
      float ss = 0.f;
#pragma unroll
      for (int nt = 0; nt < 2; ++nt)
#pragma unroll
        for (int r = 0; r < 4; ++r)
          ss += accr[s][nt][r]*accr[s][nt][r] + acci[s][nt][r]*acci[s][nt][r];
      ss += __shfl_xor(ss, 16, 64);    // sum over q (lane bits 4,5): full 32-och norm
      ss += __shfl_xor(ss, 32, 64);
      float thr = (b < BB ? thrA : thrB)[0];
      invn = 1.0f / fmaxf(sqrtf(ss), thr);
    }
    size_t pxbase = (((size_t)b*HH + y)*WW + x)*32;
#pragma unroll
    for (int nt = 0; nt < 2; ++nt) {
      size_t gb = pxbase + nt*16 + q*4;
      ull dR = 0, dI = 0;
      if constexpr (MODE == 2) {
        if (ok) { dR = *(const ull*)(derb + gb); dI = *(const ull*)(derb + PE2 + gb); }
      }
      ull vR = 0, vI = 0;
#pragma unroll
      for (int r = 0; r < 4; ++r) {
        float pr = accr[s][nt][r], pi = acci[s][nt][r];
        if constexpr (MODE == 1) { pr = actf(pr); pi = actf(pi); }
        if constexpr (MODE == 3) { pr *= invn; pi *= invn; }
        if constexpr (MODE == 2) {
          float dr = actdf(b2f((u16)(dR >> (16*r))));
          float di = actdf(b2f((u16)(dI >> (16*r))));
          float nr = pr*dr - pi*di;
          pi = pr*di + pi*dr; pr = nr;
        }
        vR |= (ull)f2b(pr) << (16*r);
        vI |= (ull)f2b(pi) << (16*r);
      }
      if (ok) {
        *(ull*)(outb + gb)       = vR;
        *(ull*)(outb + PE2 + gb) = vI;
      }
    }
  }
}

// ---------------- layer-1 forward: complex conv 1->32 + act, planar fp32 -> NHWC bf16
// 8x8 px tile; 256 threads: og = tid&3 (8 och each), px = tid>>2 (lx=px&7, ly=px>>3).
__global__ __launch_bounds__(256)
void l1fwd(const float* __restrict__ xall,
           const float* __restrict__ wrA, const float* __restrict__ wiA,
           const float* __restrict__ wrB, const float* __restrict__ wiB,
           u16* __restrict__ outb)
{
  __shared__ float hR[10][12], hI[10][12];
  __shared__ float wt[9][32][2];
  const int tid = threadIdx.x;
  const int og = tid & 3, px = tid >> 2;
  const int lx = px & 7, ly = px >> 3;
  const int x0 = blockIdx.x*8, y0 = blockIdx.y*8, b = blockIdx.z;
  const int branch = b >> 3, img = b & 7;
  const float* wr = branch ? wrB : wrA;
  const float* wi = branch ? wiB : wiA;
  const float* xp = xall + (size_t)branch*2*P1 + (size_t)img*HWSZ;

  for (int j = tid; j < 576; j += 256) {
    int tap = j >> 6; int rem = j & 63; int o = rem >> 1, ri = rem & 1;
    wt[tap][o][ri] = ri ? wi[o*9+tap] : wr[o*9+tap];
  }
  for (int j = tid; j < 200; j += 256) {
    int plane = j / 100; int pos = j - plane*100;
    int yy = pos / 10, xx = pos - yy*10;
    int gy = y0 - 1 + yy, gx = x0 - 1 + xx;
    float v = 0.f;
    if (gy >= 0 && gy < HH && gx >= 0 && gx < WW)
      v = xp[(size_t)plane*P1 + (size_t)gy*WW + gx];
    (plane ? hI : hR)[yy][xx] = v;
  }
  __syncthreads();

  float accR[8], accI[8];
#pragma unroll
  for (int o = 0; o < 8; ++o) { accR[o] = 0.f; accI[o] = 0.f; }
#pragma unroll
  for (int tap = 0; tap < 9; ++tap) {
    int ky = tap/3, kx = tap - ky*3;
    float ar = hR[ly+ky][lx+kx], ai = hI[ly+ky][lx+kx];
#pragma unroll
    for (int o = 0; o < 8; ++o) {
      float wrv = wt[tap][og*8+o][0], wiv = wt[tap][og*8+o][1];
      accR[o] += ar*wrv - ai*wiv;
      accI[o] += ar*wiv + ai*wrv;
    }
  }
  int gx = x0 + lx, gy = y0 + ly;
  if (gx < WW) {
    size_t base = (((size_t)b*HH + gy)*WW + gx)*32 + og*8;
    ull* dR = (ull*)(outb + base);
    ull* dI = (ull*)(outb + PE2 + base);
#pragma unroll
    for (int k = 0; k < 2; ++k) {
      ull vR = 0, vI = 0;
#pragma unroll
      for (int t = 0; t < 4; ++t) {
        vR |= (ull)f2b(actf(accR[k*4+t])) << (16*t);
        vI |= (ull)f2b(actf(accI[k*4+t])) << (16*t);
      }
      dR[k] = vR; dI[k] = vI;
    }
  }
}

// ---------------- layer-1 backward: complex convT 32->1, NHWC bf16 -> planar fp32 ----
// 8x8 px tile; 256 threads: cg = tid&3 (8 ch each), px = tid>>2; quad shfl reduce.
__global__ __launch_bounds__(256)
void l1bwd(const u16* __restrict__ gb,
           const float* __restrict__ wrA, const float* __restrict__ wiA,
           const float* __restrict__ wrB, const float* __restrict__ wiB,
           float* __restrict__ outp)
{
  __shared__ alignas(16) u16 stg[2*100*32];   // [plane][pos10x10][ch32] = 12.5 KB
  __shared__ float wt[32][9][2];
  const int tid = threadIdx.x;
  const int cg = tid & 3, px = tid >> 2;
  const int lx = px & 7, ly = px >> 3;
  const int x0 = blockIdx.x*8, y0 = blockIdx.y*8, b = blockIdx.z;
  const int branch = b >> 3, img = b & 7;
  const float* wr = branch ? wrB : wrA;
  const float* wi = branch ? wiB : wiA;

  for (int j = tid; j < 576; j += 256) {
    int c = j / 18; int rem = j - c*18; int tap = rem >> 1, ri = rem & 1;
    wt[c][tap][ri] = (ri ? wi : wr)[c*9 + (8-tap)];
  }
  // stage halo: 800 16B chunks (2 planes x 100 pos x 4 chq)
  for (int j = tid; j < 800; j += 256) {
    int plane = j / 400; int rem = j - plane*400;
    int pos = rem >> 2, chq = rem & 3;
    int yy = pos / 10, xx = pos - yy*10;
    int gy = y0 - 1 + yy, gx = x0 - 1 + xx;
    ull v0 = 0, v1 = 0;
    if (gy >= 0 && gy < HH && gx >= 0 && gx < WW) {
      const ull* src = (const ull*)(gb + (size_t)plane*PE2
                                    + (((size_t)b*HH + gy)*WW + gx)*32 + chq*8);
      v0 = src[0]; v1 = src[1];
    }
    ull* dst = (ull*)&stg[((size_t)plane*100 + pos)*32 + chq*8];
    dst[0] = v0; dst[1] = v1;
  }
  __syncthreads();

  float gr = 0.f, gi = 0.f;
#pragma unroll
  for (int tap = 0; tap < 9; ++tap) {
    int ky = tap/3, kx = tap - ky*3;
    int pos = (ly+ky)*10 + (lx+kx);
    const ull* pR = (const ull*)&stg[(size_t)pos*32 + cg*8];
    const ull* pI = (const ull*)&stg[(100 + (size_t)pos)*32 + cg*8];
    ull r0 = pR[0], r1 = pR[1], i0 = pI[0], i1 = pI[1];
#pragma unroll
    for (int t = 0; t < 4; ++t) {
      int c = cg*8 + t;
      float ar = b2f((u16)(r0 >> (16*t))), ai = b2f((u16)(i0 >> (16*t)));
      float wrv = wt[c][tap][0], wiv = wt[c][tap][1];
      gr += ar*wrv - ai*wiv;
      gi += ar*wiv + ai*wrv;
    }
#pragma unroll
    for (int t = 0; t < 4; ++t) {
      int c = cg*8 + 4 + t;
      float ar = b2f((u16)(r1 >> (16*t))), ai = b2f((u16)(i1 >> (16*t)));
      float wrv = wt[c][tap][0], wiv = wt[c][tap][1];
      gr += ar*wrv - ai*wiv;
      gi += ar*wiv + ai*wrv;
    }
  }
  gr += __shfl_xor(gr, 1, 64); gr += __shfl_xor(gr, 2, 64);
  gi += __shfl_xor(gi, 1, 64); gi += __shfl_xor(gi, 2, 64);

  int gx = x0 + lx, gy = y0 + ly;
  if (cg == 0 && gx < WW) {
    size_t o2 = (size_t)branch*2*P1 + (size_t)img*HWSZ + (size_t)gy*WW + gx;
    outp[o2]      = gr;
    outp[P1 + o2] = gi;
  }
}

// ---------------- DFT machinery ----------------
__global__ void gen_dft2(float2* __restrict__ Mf, float2* __restrict__ Mi, int N) {
  int idx = blockIdx.x*256 + threadIdx.x;
  if (idx >= N*N) return;
  int r = idx / N, c = idx - r*N;
  long mm = ((long)r * (long)c) % N;
  double a = 2.0 * 3.14159265358979323846 * (double)mm / (double)N;
  double cs = cos(a), sn = sin(a);
  Mf[idx] = make_float2((float)cs, (float)(-sn));
  Mi[idx] = make_float2((float)(cs/N), (float)(sn/N));
}

// row-DFT from planar x (both branches): bh over [0, 16*HH)
__global__ void dft_row_planes(const float* __restrict__ xall,
                               float2* __restrict__ out, const float2* __restrict__ M) {
  int bh = blockIdx.x;
  int v = threadIdx.x; if (v >= WW) return;
  int b2 = bh / HH, h = bh - b2*HH;
  int branch = b2 >> 3, img = b2 & 7;
  const float* rowR = xall + (size_t)branch*2*P1 + (size_t)img*HWSZ + (size_t)h*WW;
  const float* rowI = rowR + P1;
  float ar = 0.f, ai = 0.f;
  for (int w = 0; w < WW; ++w) {
    float sr = rowR[w], si = rowI[w];
    float2 m = M[w*WW + v];
    ar += sr*m.x - si*m.y;
    ai += sr*m.y + si*m.x;
  }
  out[(size_t)bh*WW + v] = make_float2(ar, ai);
}

__global__ void dft_row_c(const float2* __restrict__ in, float2* __restrict__ out,
                          const float2* __restrict__ M) {
  int bh = blockIdx.x;
  int v = threadIdx.x; if (v >= WW) return;
  const float2* row = in + (size_t)bh*WW;
  float ar = 0.f, ai = 0.f;
  for (int w = 0; w < WW; ++w) {
    float2 s = row[w];
    float2 m = M[w*WW + v];
    ar += s.x*m.x - s.y*m.y;
    ai += s.x*m.y + s.y*m.x;
  }
  out[(size_t)bh*WW + v] = make_float2(ar, ai);
}

__global__ void dft_col_c(const float2* __restrict__ in, float2* __restrict__ out,
                          const float2* __restrict__ M) {
  int bu = blockIdx.x;
  int v = threadIdx.x; if (v >= WW) return;
  int b = bu / HH, u = bu - b*HH;
  const float2* base = in + (size_t)b*HWSZ;
  float ar = 0.f, ai = 0.f;
  for (int h = 0; h < HH; ++h) {
    float2 m = M[u*HH + h];
    float2 s = base[(size_t)h*WW + v];
    ar += s.x*m.x - s.y*m.y;
    ai += s.x*m.y + s.y*m.x;
  }
  out[(size_t)bu*WW + v] = make_float2(ar, ai);
}

// col-iDFT with fused mask^2 on input element (h,v)
__global__ void dft_col_mask(const float2* __restrict__ in, float2* __restrict__ out,
                             const float2* __restrict__ M, const float* __restrict__ mask) {
  int bu = blockIdx.x;
  int v = threadIdx.x; if (v >= WW) return;
  int b = bu / HH, u = bu - b*HH;
  const float2* base = in + (size_t)b*HWSZ;
  float ar = 0.f, ai = 0.f;
  for (int h = 0; h < HH; ++h) {
    float mk = mask[h*WW + v]; float mm = mk*mk;
    float2 m = M[u*HH + h];
    float2 s = base[(size_t)h*WW + v];
    float sr = s.x*mm, si = s.y*mm;
    ar += sr*m.x - si*m.y;
    ai += sr*m.y + si*m.x;
  }
  out[(size_t)bu*WW + v] = make_float2(ar, ai);
}

// final row-iDFT fused with x update: x -= a*(gradf - ct) + bet*gr
__global__ void dft_row_update(const float2* __restrict__ in, const float2* __restrict__ M,
                               const float2* __restrict__ ctall, const float* __restrict__ grp,
                               float* __restrict__ xall,
                               const float* __restrict__ al1, const float* __restrict__ al2,
                               const float* __restrict__ be1, const float* __restrict__ be2,
                               int phase) {
  int bh = blockIdx.x;
  int v = threadIdx.x; if (v >= WW) return;
  int b2 = bh / HH, h = bh - b2*HH;
  int branch = b2 >> 3, img = b2 & 7;
  const float2* row = in + (size_t)bh*WW;
  float ar = 0.f, ai = 0.f;
  for (int w = 0; w < WW; ++w) {
    float2 s = row[w];
    float2 m = M[w*WW + v];
    ar += s.x*m.x - s.y*m.y;
    ai += s.x*m.y + s.y*m.x;
  }
  float2 ct = ctall[(size_t)bh*WW + v];
  float a   = (branch ? al2 : al1)[phase];
  float bet = (branch ? be2 : be1)[phase];
  size_t xo = (size_t)branch*2*P1 + (size_t)img*HWSZ + (size_t)h*WW + v;
  xall[xo]      -= a*(ar - ct.x) + bet*grp[xo];
  xall[P1 + xo] -= a*(ai - ct.y) + bet*grp[P1 + xo];
}

// ---------------- small pointwise kernels ----------------
__global__ void maskk_m(const float* __restrict__ k1, const float* __restrict__ k2,
                        const float* __restrict__ mask, float2* __restrict__ t) {
  int i = blockIdx.x*256 + threadIdx.x;
  if (i >= (int)(2*P1)) return;
  int branch = i >= (int)P1;
  int ii = i - branch*(int)P1;
  int b = ii / HWSZ, p = ii - b*HWSZ;
  const float* k = branch ? k2 : k1;
  float m = mask[p];
  t[i] = make_float2(m * k[(size_t)b*2*HWSZ + p], m * k[(size_t)b*2*HWSZ + HWSZ + p]);
}

__global__ void unpack_m(const float* __restrict__ x1, const float* __restrict__ x2,
                         float* __restrict__ xall) {
  int i = blockIdx.x*256 + threadIdx.x;
  if (i >= (int)(2*P1)) return;
  int branch = i >= (int)P1;
  int ii = i - branch*(int)P1;
  int b = ii / HWSZ, p = ii - b*HWSZ;
  const float* src = branch ? x2 : x1;
  size_t dst = (size_t)branch*2*P1 + (size_t)b*HWSZ + p;
  xall[dst]      = src[(size_t)b*2*HWSZ + p];
  xall[P1 + dst] = src[(size_t)b*2*HWSZ + HWSZ + p];
}

__global__ void pack_kernel(const float* __restrict__ xall, float* __restrict__ out) {
  int i = blockIdx.x*256 + threadIdx.x;
  if (i >= (int)P1) return;
  int b = i / HWSZ, p = i - b*HWSZ;
  size_t ob = (size_t)b*4*HWSZ;
  size_t x1o = (size_t)b*HWSZ + p;
  size_t x2o = 2*P1 + x1o;
  out[ob + p]          = xall[x1o];
  out[ob + HWSZ + p]   = xall[P1 + x1o];
  out[ob + 2*HWSZ + p] = xall[x2o];
  out[ob + 3*HWSZ + p] = xall[P1 + x2o];
}

// ---------------- launch ----------------
extern "C" void kernel_launch(void* const* d_in, const int* in_sizes, int n_in,
                              void* d_out, int out_size, void* d_ws, size_t ws_size,
                              hipStream_t stream) {
  (void)in_sizes; (void)n_in; (void)out_size; (void)ws_size;
  const float* x1in = (const float*)d_in[0];
  const float* x2in = (const float*)d_in[1];
  const float* k1   = (const float*)d_in[2];
  const float* k2   = (const float*)d_in[3];
  const float* mask = (const float*)d_in[4];
  Ptrs16 cw;
  for (int i = 0; i < 16; ++i) cw.p[i] = (const float*)d_in[5+i];
  const float* thr1 = (const float*)d_in[21];
  const float* thr2 = (const float*)d_in[22];
  const float* al1  = (const float*)d_in[23];
  const float* al2  = (const float*)d_in[24];
  const float* be1  = (const float*)d_in[25];
  const float* be2  = (const float*)d_in[26];
  float* out = (float*)d_out;

  // ---- workspace: bf16 region then fp32 region ----
  u16* U = (u16*)d_ws;
  size_t uoff = 0;
  auto alloc_u = [&](size_t n){ u16* p = U + uoff; uoff += (n + 15) & ~(size_t)15; return p; };
  u16* act1 = alloc_u(2*PE2);
  u16* act2 = alloc_u(2*PE2);
  u16* act3 = alloc_u(2*PE2);
  u16* w4b  = alloc_u(2*PE2);
  u16* wp0  = alloc_u(12*18432);

  float* F = (float*)(U + uoff);
  size_t off = 0;
  auto alloc_f = [&](size_t n){ float* p = F + off; off += (n + 3) & ~(size_t)3; return p; };
  float*  xall = alloc_f(4*P1);                       // [branch][plane][P1]
  float*  grp  = alloc_f(4*P1);
  float2* t1   = (float2*)alloc_f(4*P1);              // [16][HWSZ] complex
  float2* t2   = (float2*)alloc_f(4*P1);
  float2* ctall= (float2*)alloc_f(4*P1);
  float2* EWf  = (float2*)alloc_f(2*(size_t)WW*WW);
  float2* EWi  = (float2*)alloc_f(2*(size_t)WW*WW);
  float2* EHf  = (float2*)alloc_f(2*(size_t)HH*HH);
  float2* EHi  = (float2*)alloc_f(2*(size_t)HH*HH);

  const dim3 MG(6, 40, BB2);      // conv: 32x4 tiles, both branches (3840 blocks)
  const dim3 LG(23, 20, BB2);     // l1 convs: 8x8 tiles
  const int NP1 = (int)((P1 + 255)/256);
  const int NP2 = (int)((2*P1 + 255)/256);
  const int DFTG = BB2*HH;        // 2560
  const int DFTB = 192;

  gen_dft2<<<(WW*WW+255)/256, 256, 0, stream>>>(EWf, EWi, WW);
  gen_dft2<<<(HH*HH+255)/256, 256, 0, stream>>>(EHf, EHi, HH);
  prep_all<<<12*36, 256, 0, stream>>>(cw, wp0);
  unpack_m<<<NP2, 256, 0, stream>>>(x1in, x2in, xall);

  // cterm = ifft2(mask*k), both branches
  maskk_m<<<NP2, 256, 0, stream>>>(k1, k2, mask, t1);
  dft_col_c<<<DFTG, DFTB, 0, stream>>>(t1, t2, EHi);
  dft_row_c<<<DFTG, DFTB, 0, stream>>>(t2, ctall, EWi);

  u16* WA[6]; u16* WB[6];
  for (int i = 0; i < 6; ++i) { WA[i] = wp0 + (size_t)i*18432; WB[i] = wp0 + (size_t)(6+i)*18432; }

  for (int ph = 0; ph < 3; ++ph) {
    // grad_r both branches
    l1fwd<<<LG, 256, 0, stream>>>(xall, cw.p[0], cw.p[1], cw.p[8], cw.p[9], act1);
    conv_mfma<1><<<MG, 256, 0, stream>>>(act1, WA[0], WB[0], act2, nullptr, nullptr, nullptr);
    conv_mfma<1><<<MG, 256, 0, stream>>>(act2, WA[1], WB[1], act3, nullptr, nullptr, nullptr);
    conv_mfma<3><<<MG, 256, 0, stream>>>(act3, WA[2], WB[2], w4b, nullptr, thr1, thr2);
    conv_mfma<2><<<MG, 256, 0, stream>>>(w4b,  WA[3], WB[3], act3, act3, nullptr, nullptr);
    conv_mfma<2><<<MG, 256, 0, stream>>>(act3, WA[4], WB[4], act2, act2, nullptr, nullptr);
    conv_mfma<2><<<MG, 256, 0, stream>>>(act2, WA[5], WB[5], act1, act1, nullptr, nullptr);
    l1bwd<<<LG, 256, 0, stream>>>(act1, cw.p[0], cw.p[1], cw.p[8], cw.p[9], grp);
    // grad_f both branches + fused update
    dft_row_planes<<<DFTG, DFTB, 0, stream>>>(xall, t1, EWf);
    dft_col_c<<<DFTG, DFTB, 0, stream>>>(t1, t2, EHf);
    dft_col_mask<<<DFTG, DFTB, 0, stream>>>(t2, t1, EHi, mask);
    dft_row_update<<<DFTG, DFTB, 0, stream>>>(t1, EWi, ctall, grp, xall,
                                              al1, al2, be1, be2, ph);
  }

  pack_kernel<<<NP1, 256, 0, stream>>>(xall, out);
}